// Round 4
// baseline (345.882 us; speedup 1.0000x reference)
//
#include <hip/hip_runtime.h>

#define BLOCK 256
// 4 rows/thread = two independent float2 streams (A,B), packed v_pk_fma_f32.
// Weights pre-duplicated {w,w} in d_ws (R3): uniform 64-bit load -> SGPR pair
// -> legal VOP3P source, zero broadcast movs. Interleaving streams A/B gives
// 2 independent FMA chains per weight: covers the ~4cy pk_fma latency (R3 was
// one chain -> <=50% issue ceiling, measured 48% VALUBusy) and amortizes
// weight s_loads 4 rows deep.
// __launch_bounds__(256,4): VGPR cap 128, tells the scheduler to target
// 4 waves/SIMD instead of squeezing to 40 VGPRs by serializing chains.
// All locals are 1D constant-indexed v2f arrays (SROA size class proven in
// R0/R3; the [4][16] aggregates of R1 went to scratch -> 10x regression).

typedef float v2f __attribute__((ext_vector_type(2)));

struct WPtrs {
    const float* w[19];
    const float* b[19];
};

struct WDup {            // pointers into d_ws: duplicated {v,v} pairs
    const v2f* w[19];
    const v2f* b[19];
};

enum LId {FU1,FU2,KU1,KU2,HU1,HU2,MD1,MD2,MD3,HD1,HD2,KD1,KD2,HA1,HA2,KA1,KA2,FA1,FA2};

__constant__ const int kWN[19] = {4,4,16,16,36,36,176,256,96,24,16,8,4,32,4,24,4,16,4};
__constant__ const int kBN[19] = {2,2,4,4,6,6,16,16,6,4,4,2,2,4,1,4,1,4,1};

// ---- prep: duplicate weights+biases into ws as {v,v}; one block per layer ----
__global__ void prep_kernel(WPtrs P, float* __restrict__ ws) {
    const int l = blockIdx.x;
    const int t = threadIdx.x;
    int off = 0;
    for (int i = 0; i < l; ++i) off += 2 * (kWN[i] + kBN[i]);
    float* dw = ws + off;
    const int wn = kWN[l];
    for (int i = t; i < wn; i += BLOCK) {
        const float v = P.w[l][i];
        dw[2*i] = v; dw[2*i+1] = v;
    }
    float* db = dw + 2*wn;
    const int bn = kBN[l];
    for (int i = t; i < bn; i += BLOCK) {
        const float v = P.b[l][i];
        db[2*i] = v; db[2*i+1] = v;
    }
}

// Two independent row-pair streams through one layer; FMAs interleaved A/B so
// each weight (SGPR pair) feeds two independent v_pk_fma_f32.
template<int DIN,int DOUT,bool RELU>
__device__ __forceinline__ void lin4(const v2f (&inA)[DIN], const v2f (&inB)[DIN],
                                     v2f (&outA)[DOUT], v2f (&outB)[DOUT],
                                     const v2f* __restrict__ wd, const v2f* __restrict__ bd) {
#pragma unroll
    for (int j = 0; j < DOUT; ++j) {
        v2f accA = bd[j];
        v2f accB = bd[j];
#pragma unroll
        for (int i = 0; i < DIN; ++i) {
            const v2f wv = wd[i*DOUT + j];
            accA = __builtin_elementwise_fma(inA[i], wv, accA);
            accB = __builtin_elementwise_fma(inB[i], wv, accB);
        }
        if (RELU) {
            const v2f z = {0.0f, 0.0f};
            accA = __builtin_elementwise_max(accA, z);
            accB = __builtin_elementwise_max(accB, z);
        }
        outA[j] = accA;
        outB[j] = accB;
    }
}

__global__ __launch_bounds__(BLOCK, 4) void pnet_kernel(
    const float* __restrict__ x, float* __restrict__ out, int B, WDup P) {
    const int tid = threadIdx.x;
    const int r0 = blockIdx.x * (BLOCK * 4) + tid;   // rows r0, r0+B, r0+2B, r0+3B
    const int r1 = r0 + BLOCK;
    const int r2 = r0 + 2*BLOCK;
    const int r3 = r0 + 3*BLOCK;

    const int c0 = r0 < B ? r0 : (B - 1);   // clamp loads; stores guarded below
    const int c1 = r1 < B ? r1 : (B - 1);
    const int c2 = r2 < B ? r2 : (B - 1);
    const int c3 = r3 < B ? r3 : (B - 1);
    const float* p0 = x + (long long)c0 * 11;
    const float* p1 = x + (long long)c1 * 11;
    const float* p2 = x + (long long)c2 * 11;
    const float* p3 = x + (long long)c3 * 11;

    v2f xinA[11], xinB[11];
#pragma unroll
    for (int c = 0; c < 11; ++c) {
        xinA[c].x = p0[c]; xinA[c].y = p1[c];
        xinB[c].x = p2[c]; xinB[c].y = p3[c];
    }

    // ---- f_up: [f, fd] -> 2 -> 2 ----
    v2f finA[2] = {xinA[4], xinA[10]}, finB[2] = {xinB[4], xinB[10]};
    v2f tfA[2], tfB[2], f_upA[2], f_upB[2];
    lin4<2,2,true>(finA, finB, tfA, tfB, P.w[FU1], P.b[FU1]);
    lin4<2,2,true>(tfA, tfB, f_upA, f_upB, P.w[FU2], P.b[FU2]);

    // ---- k_up: [k, kd, f_up] -> 4 -> 4 ----
    v2f kinA[4] = {xinA[3], xinA[9], f_upA[0], f_upA[1]};
    v2f kinB[4] = {xinB[3], xinB[9], f_upB[0], f_upB[1]};
    v2f tkA[4], tkB[4], k_upA[4], k_upB[4];
    lin4<4,4,true>(kinA, kinB, tkA, tkB, P.w[KU1], P.b[KU1]);
    lin4<4,4,true>(tkA, tkB, k_upA, k_upB, P.w[KU2], P.b[KU2]);

    // ---- h_up: [h, hd, k_up] -> 6 -> 6 ----
    v2f hinA[6] = {xinA[2], xinA[8], k_upA[0], k_upA[1], k_upA[2], k_upA[3]};
    v2f hinB[6] = {xinB[2], xinB[8], k_upB[0], k_upB[1], k_upB[2], k_upB[3]};
    v2f thA[6], thB[6], h_upA[6], h_upB[6];
    lin4<6,6,true>(hinA, hinB, thA, thB, P.w[HU1], P.b[HU1]);
    lin4<6,6,true>(thA, thB, h_upA, h_upB, P.w[HU2], P.b[HU2]);

    // ---- m_down: [m_obs(5), h_up(6)] -> 16 -> 16 -> 6 ----
    v2f minA[11] = {xinA[0], xinA[1], xinA[5], xinA[6], xinA[7],
                    h_upA[0], h_upA[1], h_upA[2], h_upA[3], h_upA[4], h_upA[5]};
    v2f minB[11] = {xinB[0], xinB[1], xinB[5], xinB[6], xinB[7],
                    h_upB[0], h_upB[1], h_upB[2], h_upB[3], h_upB[4], h_upB[5]};
    v2f t16aA[16], t16aB[16], t16bA[16], t16bB[16], m_downA[6], m_downB[6];
    lin4<11,16,true>(minA, minB, t16aA, t16aB, P.w[MD1], P.b[MD1]);
    lin4<16,16,true>(t16aA, t16aB, t16bA, t16bB, P.w[MD2], P.b[MD2]);
    lin4<16,6,true>(t16bA, t16bB, m_downA, m_downB, P.w[MD3], P.b[MD3]);

    // ---- h_down: m_down -> 4 -> 4 ----
    v2f t4bA[4], t4bB[4], h_downA[4], h_downB[4];
    lin4<6,4,true>(m_downA, m_downB, t4bA, t4bB, P.w[HD1], P.b[HD1]);
    lin4<4,4,true>(t4bA, t4bB, h_downA, h_downB, P.w[HD2], P.b[HD2]);

    // ---- k_down: h_down -> 2 -> 2 ----
    v2f t2bA[2], t2bB[2], k_downA[2], k_downB[2];
    lin4<4,2,true>(h_downA, h_downB, t2bA, t2bB, P.w[KD1], P.b[KD1]);
    lin4<2,2,true>(t2bA, t2bB, k_downA, k_downB, P.w[KD2], P.b[KD2]);

    // ---- h_act: [h, hd, m_down(6)] -> 4 -> 1 (no relu on last) ----
    v2f haA[8] = {xinA[2], xinA[8], m_downA[0], m_downA[1],
                  m_downA[2], m_downA[3], m_downA[4], m_downA[5]};
    v2f haB[8] = {xinB[2], xinB[8], m_downB[0], m_downB[1],
                  m_downB[2], m_downB[3], m_downB[4], m_downB[5]};
    v2f t4cA[4], t4cB[4], h_actA[1], h_actB[1];
    lin4<8,4,true>(haA, haB, t4cA, t4cB, P.w[HA1], P.b[HA1]);
    lin4<4,1,false>(t4cA, t4cB, h_actA, h_actB, P.w[HA2], P.b[HA2]);

    // ---- k_act: [k, kd, h_down(4)] -> 4 -> 1 ----
    v2f kaA[6] = {xinA[3], xinA[9], h_downA[0], h_downA[1], h_downA[2], h_downA[3]};
    v2f kaB[6] = {xinB[3], xinB[9], h_downB[0], h_downB[1], h_downB[2], h_downB[3]};
    v2f t4dA[4], t4dB[4], k_actA[1], k_actB[1];
    lin4<6,4,true>(kaA, kaB, t4dA, t4dB, P.w[KA1], P.b[KA1]);
    lin4<4,1,false>(t4dA, t4dB, k_actA, k_actB, P.w[KA2], P.b[KA2]);

    // ---- f_act: [f, fd, k_down(2)] -> 4 -> 1 ----
    v2f faA[4] = {xinA[4], xinA[10], k_downA[0], k_downA[1]};
    v2f faB[4] = {xinB[4], xinB[10], k_downB[0], k_downB[1]};
    v2f t4eA[4], t4eB[4], f_actA[1], f_actB[1];
    lin4<4,4,true>(faA, faB, t4eA, t4eB, P.w[FA1], P.b[FA1]);
    lin4<4,1,false>(t4eA, t4eB, f_actA, f_actB, P.w[FA2], P.b[FA2]);

    // ---- store: [h_act, f_act, k_act] per row (guarded for tail) ----
    if (r0 < B) { float* po = out + (long long)r0 * 3;
        po[0] = h_actA[0].x; po[1] = f_actA[0].x; po[2] = k_actA[0].x; }
    if (r1 < B) { float* po = out + (long long)r1 * 3;
        po[0] = h_actA[0].y; po[1] = f_actA[0].y; po[2] = k_actA[0].y; }
    if (r2 < B) { float* po = out + (long long)r2 * 3;
        po[0] = h_actB[0].x; po[1] = f_actB[0].x; po[2] = k_actB[0].x; }
    if (r3 < B) { float* po = out + (long long)r3 * 3;
        po[0] = h_actB[0].y; po[1] = f_actB[0].y; po[2] = k_actB[0].y; }
}

extern "C" void kernel_launch(void* const* d_in, const int* in_sizes, int n_in,
                              void* d_out, int out_size, void* d_ws, size_t ws_size,
                              hipStream_t stream) {
    static const int wn[19] = {4,4,16,16,36,36,176,256,96,24,16,8,4,32,4,24,4,16,4};
    static const int bn[19] = {2,2,4,4,6,6,16,16,6,4,4,2,2,4,1,4,1,4,1};

    const float* x = (const float*)d_in[0];
    float* out = (float*)d_out;
    const int B = in_sizes[0] / 11;

    WPtrs P;
    for (int i = 0; i < 19; ++i) {
        P.w[i] = (const float*)d_in[1 + 2*i];
        P.b[i] = (const float*)d_in[2 + 2*i];
    }

    float* ws = (float*)d_ws;
    WDup D;
    int off = 0;
    for (int l = 0; l < 19; ++l) {
        D.w[l] = (const v2f*)(ws + off); off += 2 * wn[l];
        D.b[l] = (const v2f*)(ws + off); off += 2 * bn[l];
    }

    prep_kernel<<<19, BLOCK, 0, stream>>>(P, ws);   // one block per layer, ~2 us

    const long long rows_per_block = (long long)BLOCK * 4;
    const int blocks = (int)((B + rows_per_block - 1) / rows_per_block);
    pnet_kernel<<<blocks, BLOCK, 0, stream>>>(x, out, B, D);
}

// Round 5
// 325.234 us; speedup vs baseline: 1.0635x; 1.0635x over previous
//
#include <hip/hip_runtime.h>

#define BLOCK 256
#define GRID_BLOCKS 2048   // 8 blocks/CU at VGPR<=64: full 32-wave/CU residency
// Persistent grid-stride version of the R3 kernel (best proven: 55.6us, VGPR=40,
// zero scratch). R3 post-mortem: stall time is a CONSTANT ~25-29us across all
// variants (R0 21, R2 29, R3 29) -- per-wave serialized weight s_load waits,
// uncovered at ~3.6 resident waves/SIMD (two dispatch rounds + ramp/tail).
// Fix: one resident grid (2048 blocks = 8/CU), each thread loops over row-pairs.
// Compute body is R3 verbatim: 2 rows/thread packed v2f, weights pre-duplicated
// {w,w} in d_ws (uniform 64-bit s_load -> SGPR pair -> legal VOP3P src, zero
// broadcast movs). R4 lesson: total alloca must stay ~1.1KB/thread -- the
// two-stream variant (2.3KB) was demoted to scratch (WRITE_SIZE 23->64MB).

typedef float v2f __attribute__((ext_vector_type(2)));

struct WPtrs {
    const float* w[19];
    const float* b[19];
};

struct WDup {            // pointers into d_ws: duplicated {v,v} pairs
    const v2f* w[19];
    const v2f* b[19];
};

enum LId {FU1,FU2,KU1,KU2,HU1,HU2,MD1,MD2,MD3,HD1,HD2,KD1,KD2,HA1,HA2,KA1,KA2,FA1,FA2};

__constant__ const int kWN[19] = {4,4,16,16,36,36,176,256,96,24,16,8,4,32,4,24,4,16,4};
__constant__ const int kBN[19] = {2,2,4,4,6,6,16,16,6,4,4,2,2,4,1,4,1,4,1};

// ---- prep: duplicate weights+biases into ws as {v,v}; one block per layer ----
__global__ void prep_kernel(WPtrs P, float* __restrict__ ws) {
    const int l = blockIdx.x;
    const int t = threadIdx.x;
    int off = 0;
    for (int i = 0; i < l; ++i) off += 2 * (kWN[i] + kBN[i]);
    float* dw = ws + off;
    const int wn = kWN[l];
    for (int i = t; i < wn; i += BLOCK) {
        const float v = P.w[l][i];
        dw[2*i] = v; dw[2*i+1] = v;
    }
    float* db = dw + 2*wn;
    const int bn = kBN[l];
    for (int i = t; i < bn; i += BLOCK) {
        const float v = P.b[l][i];
        db[2*i] = v; db[2*i+1] = v;
    }
}

template<int DIN,int DOUT,bool RELU>
__device__ __forceinline__ void lin2(const v2f (&in)[DIN], v2f (&out)[DOUT],
                                     const v2f* __restrict__ wd, const v2f* __restrict__ bd) {
#pragma unroll
    for (int j = 0; j < DOUT; ++j) {
        v2f acc = bd[j];                          // {b,b}: SGPR pair
#pragma unroll
        for (int i = 0; i < DIN; ++i)
            acc = __builtin_elementwise_fma(in[i], wd[i*DOUT + j], acc); // v_pk_fma_f32
        if (RELU) {
            const v2f z = {0.0f, 0.0f};
            acc = __builtin_elementwise_max(acc, z);                     // v_pk_max_f32
        }
        out[j] = acc;
    }
}

__global__ __launch_bounds__(BLOCK) void pnet_kernel(
    const float* __restrict__ x, float* __restrict__ out, int B, WDup P) {
    const int tid = threadIdx.x;
    const long long stride = (long long)gridDim.x * (BLOCK * 2);

    for (long long base = (long long)blockIdx.x * (BLOCK * 2); base < B; base += stride) {
        const long long rowA = base + tid;
        const long long rowB = rowA + BLOCK;

        const long long cA = rowA < B ? rowA : (B - 1);   // clamp loads; stores guarded
        const long long cB = rowB < B ? rowB : (B - 1);
        const float* pA = x + cA * 11;
        const float* pB = x + cB * 11;
        v2f xin[11];
#pragma unroll
        for (int c = 0; c < 11; ++c) { xin[c].x = pA[c]; xin[c].y = pB[c]; }

        // ---- f_up: [f, fd] -> 2 -> 2 ----
        v2f fin[2] = {xin[4], xin[10]};
        v2f tf[2], f_up[2];
        lin2<2,2,true>(fin, tf, P.w[FU1], P.b[FU1]);
        lin2<2,2,true>(tf, f_up, P.w[FU2], P.b[FU2]);

        // ---- k_up: [k, kd, f_up] -> 4 -> 4 ----
        v2f kin[4] = {xin[3], xin[9], f_up[0], f_up[1]};
        v2f tk[4], k_up[4];
        lin2<4,4,true>(kin, tk, P.w[KU1], P.b[KU1]);
        lin2<4,4,true>(tk, k_up, P.w[KU2], P.b[KU2]);

        // ---- h_up: [h, hd, k_up] -> 6 -> 6 ----
        v2f hin[6] = {xin[2], xin[8], k_up[0], k_up[1], k_up[2], k_up[3]};
        v2f th[6], h_up[6];
        lin2<6,6,true>(hin, th, P.w[HU1], P.b[HU1]);
        lin2<6,6,true>(th, h_up, P.w[HU2], P.b[HU2]);

        // ---- m_down: [m_obs(5), h_up(6)] -> 16 -> 16 -> 6 ----
        v2f min_[11] = {xin[0], xin[1], xin[5], xin[6], xin[7],
                        h_up[0], h_up[1], h_up[2], h_up[3], h_up[4], h_up[5]};
        v2f t16a[16], t16b[16], m_down[6];
        lin2<11,16,true>(min_, t16a, P.w[MD1], P.b[MD1]);
        lin2<16,16,true>(t16a, t16b, P.w[MD2], P.b[MD2]);
        lin2<16,6,true>(t16b, m_down, P.w[MD3], P.b[MD3]);

        // ---- h_down: m_down -> 4 -> 4 ----
        v2f t4b[4], h_down[4];
        lin2<6,4,true>(m_down, t4b, P.w[HD1], P.b[HD1]);
        lin2<4,4,true>(t4b, h_down, P.w[HD2], P.b[HD2]);

        // ---- k_down: h_down -> 2 -> 2 ----
        v2f t2b[2], k_down[2];
        lin2<4,2,true>(h_down, t2b, P.w[KD1], P.b[KD1]);
        lin2<2,2,true>(t2b, k_down, P.w[KD2], P.b[KD2]);

        // ---- h_act: [h, hd, m_down(6)] -> 4 -> 1 (no relu on last) ----
        v2f ha_in[8] = {xin[2], xin[8], m_down[0], m_down[1],
                        m_down[2], m_down[3], m_down[4], m_down[5]};
        v2f t4c[4], h_act[1];
        lin2<8,4,true>(ha_in, t4c, P.w[HA1], P.b[HA1]);
        lin2<4,1,false>(t4c, h_act, P.w[HA2], P.b[HA2]);   // acc pair = {rowA, rowB}

        // ---- k_act: [k, kd, h_down(4)] -> 4 -> 1 ----
        v2f ka_in[6] = {xin[3], xin[9], h_down[0], h_down[1], h_down[2], h_down[3]};
        v2f t4d[4], k_act[1];
        lin2<6,4,true>(ka_in, t4d, P.w[KA1], P.b[KA1]);
        lin2<4,1,false>(t4d, k_act, P.w[KA2], P.b[KA2]);

        // ---- f_act: [f, fd, k_down(2)] -> 4 -> 1 ----
        v2f fa_in[4] = {xin[4], xin[10], k_down[0], k_down[1]};
        v2f t4e[4], f_act[1];
        lin2<4,4,true>(fa_in, t4e, P.w[FA1], P.b[FA1]);
        lin2<4,1,false>(t4e, f_act, P.w[FA2], P.b[FA2]);

        // ---- store: [h_act, f_act, k_act] per row (guarded for tail) ----
        if (rowA < B) { float* po = out + rowA * 3;
            po[0] = h_act[0].x; po[1] = f_act[0].x; po[2] = k_act[0].x; }
        if (rowB < B) { float* po = out + rowB * 3;
            po[0] = h_act[0].y; po[1] = f_act[0].y; po[2] = k_act[0].y; }
    }
}

extern "C" void kernel_launch(void* const* d_in, const int* in_sizes, int n_in,
                              void* d_out, int out_size, void* d_ws, size_t ws_size,
                              hipStream_t stream) {
    static const int wn[19] = {4,4,16,16,36,36,176,256,96,24,16,8,4,32,4,24,4,16,4};
    static const int bn[19] = {2,2,4,4,6,6,16,16,6,4,4,2,2,4,1,4,1,4,1};

    const float* x = (const float*)d_in[0];
    float* out = (float*)d_out;
    const int B = in_sizes[0] / 11;

    WPtrs P;
    for (int i = 0; i < 19; ++i) {
        P.w[i] = (const float*)d_in[1 + 2*i];
        P.b[i] = (const float*)d_in[2 + 2*i];
    }

    float* ws = (float*)d_ws;
    WDup D;
    int off = 0;
    for (int l = 0; l < 19; ++l) {
        D.w[l] = (const v2f*)(ws + off); off += 2 * wn[l];
        D.b[l] = (const v2f*)(ws + off); off += 2 * bn[l];
    }

    prep_kernel<<<19, BLOCK, 0, stream>>>(P, ws);   // one block per layer, ~2 us

    const long long pairs_per_block = (long long)BLOCK * 2;
    const long long need = (B + pairs_per_block - 1) / pairs_per_block;
    const int blocks = (int)(need < GRID_BLOCKS ? need : GRID_BLOCKS);
    pnet_kernel<<<blocks, BLOCK, 0, stream>>>(x, out, B, D);
}

// Round 6
// 229.241 us; speedup vs baseline: 1.5088x; 1.4187x over previous
//
#include <hip/hip_runtime.h>

#define BLOCK 256
// R3 shell (proven 55.6us, VGPR=40, zero scratch): one row-pair per thread in
// float2 lanes -> v_pk_fma_f32; weights pre-duplicated {w,w} in d_ws so each
// weight is a uniform 64-bit s_load -> SGPR pair -> legal VOP3P src (no movs).
//
// R5 lesson: persistent grid-stride loop poisoned codegen (LICM + SGPR spill
// -> VALU-busy time 4.3x). One-shot launch restored.
// R3 limiter: VALUBusy 48% == the 50% issue ceiling of a SINGLE dependent
// pk_fma chain (4cy latency / 2cy issue) -- j-outer loops serialize each
// output's chain and the allocator (at VGPR=40) declined to interleave.
// Fix here: i-outer / j-inner loop nest. Program order is acc0+=,acc1+=,...
// accDOUT-1+= -- up to 16 independent chains back-to-back (MD2), covering
// pk_fma latency by construction. Same inst count; pure scheduling fix.
// All locals remain <=16-element constant-indexed v2f arrays (SROA-proven;
// R1/R4 showed bigger aggregates get demoted to scratch).

typedef float v2f __attribute__((ext_vector_type(2)));

struct WPtrs {
    const float* w[19];
    const float* b[19];
};

struct WDup {            // pointers into d_ws: duplicated {v,v} pairs
    const v2f* w[19];
    const v2f* b[19];
};

enum LId {FU1,FU2,KU1,KU2,HU1,HU2,MD1,MD2,MD3,HD1,HD2,KD1,KD2,HA1,HA2,KA1,KA2,FA1,FA2};

__constant__ const int kWN[19] = {4,4,16,16,36,36,176,256,96,24,16,8,4,32,4,24,4,16,4};
__constant__ const int kBN[19] = {2,2,4,4,6,6,16,16,6,4,4,2,2,4,1,4,1,4,1};

// ---- prep: duplicate weights+biases into ws as {v,v}; one block per layer ----
__global__ void prep_kernel(WPtrs P, float* __restrict__ ws) {
    const int l = blockIdx.x;
    const int t = threadIdx.x;
    int off = 0;
    for (int i = 0; i < l; ++i) off += 2 * (kWN[i] + kBN[i]);
    float* dw = ws + off;
    const int wn = kWN[l];
    for (int i = t; i < wn; i += BLOCK) {
        const float v = P.w[l][i];
        dw[2*i] = v; dw[2*i+1] = v;
    }
    float* db = dw + 2*wn;
    const int bn = kBN[l];
    for (int i = t; i < bn; i += BLOCK) {
        const float v = P.b[l][i];
        db[2*i] = v; db[2*i+1] = v;
    }
}

// i-outer / j-inner: all DOUT accumulator chains are interleaved in program
// order -> DOUT-way ILP per weight row, covers v_pk_fma_f32 latency.
template<int DIN,int DOUT,bool RELU>
__device__ __forceinline__ void lin2(const v2f (&in)[DIN], v2f (&out)[DOUT],
                                     const v2f* __restrict__ wd, const v2f* __restrict__ bd) {
    v2f acc[DOUT];
#pragma unroll
    for (int j = 0; j < DOUT; ++j) acc[j] = bd[j];      // {b,b}: SGPR pair
#pragma unroll
    for (int i = 0; i < DIN; ++i) {
        const v2f xi = in[i];
#pragma unroll
        for (int j = 0; j < DOUT; ++j)
            acc[j] = __builtin_elementwise_fma(xi, wd[i*DOUT + j], acc[j]); // v_pk_fma_f32
    }
#pragma unroll
    for (int j = 0; j < DOUT; ++j) {
        if (RELU) {
            const v2f z = {0.0f, 0.0f};
            out[j] = __builtin_elementwise_max(acc[j], z);                  // v_pk_max_f32
        } else {
            out[j] = acc[j];
        }
    }
}

__global__ __launch_bounds__(BLOCK) void pnet_kernel(
    const float* __restrict__ x, float* __restrict__ out, int B, WDup P) {
    const int tid  = threadIdx.x;
    const int rowA = blockIdx.x * (BLOCK * 2) + tid;
    const int rowB = rowA + BLOCK;

    const int rA = rowA < B ? rowA : (B - 1);   // clamp loads; stores guarded below
    const int rB = rowB < B ? rowB : (B - 1);
    const float* pA = x + (long long)rA * 11;
    const float* pB = x + (long long)rB * 11;
    v2f xin[11];
#pragma unroll
    for (int c = 0; c < 11; ++c) { xin[c].x = pA[c]; xin[c].y = pB[c]; }

    // ---- f_up: [f, fd] -> 2 -> 2 ----
    v2f fin[2] = {xin[4], xin[10]};
    v2f tf[2], f_up[2];
    lin2<2,2,true>(fin, tf, P.w[FU1], P.b[FU1]);
    lin2<2,2,true>(tf, f_up, P.w[FU2], P.b[FU2]);

    // ---- k_up: [k, kd, f_up] -> 4 -> 4 ----
    v2f kin[4] = {xin[3], xin[9], f_up[0], f_up[1]};
    v2f tk[4], k_up[4];
    lin2<4,4,true>(kin, tk, P.w[KU1], P.b[KU1]);
    lin2<4,4,true>(tk, k_up, P.w[KU2], P.b[KU2]);

    // ---- h_up: [h, hd, k_up] -> 6 -> 6 ----
    v2f hin[6] = {xin[2], xin[8], k_up[0], k_up[1], k_up[2], k_up[3]};
    v2f th[6], h_up[6];
    lin2<6,6,true>(hin, th, P.w[HU1], P.b[HU1]);
    lin2<6,6,true>(th, h_up, P.w[HU2], P.b[HU2]);

    // ---- m_down: [m_obs(5), h_up(6)] -> 16 -> 16 -> 6 ----
    v2f min_[11] = {xin[0], xin[1], xin[5], xin[6], xin[7],
                    h_up[0], h_up[1], h_up[2], h_up[3], h_up[4], h_up[5]};
    v2f t16a[16], t16b[16], m_down[6];
    lin2<11,16,true>(min_, t16a, P.w[MD1], P.b[MD1]);
    lin2<16,16,true>(t16a, t16b, P.w[MD2], P.b[MD2]);
    lin2<16,6,true>(t16b, m_down, P.w[MD3], P.b[MD3]);

    // ---- h_down: m_down -> 4 -> 4 ----
    v2f t4b[4], h_down[4];
    lin2<6,4,true>(m_down, t4b, P.w[HD1], P.b[HD1]);
    lin2<4,4,true>(t4b, h_down, P.w[HD2], P.b[HD2]);

    // ---- k_down: h_down -> 2 -> 2 ----
    v2f t2b[2], k_down[2];
    lin2<4,2,true>(h_down, t2b, P.w[KD1], P.b[KD1]);
    lin2<2,2,true>(t2b, k_down, P.w[KD2], P.b[KD2]);

    // ---- h_act: [h, hd, m_down(6)] -> 4 -> 1 (no relu on last) ----
    v2f ha_in[8] = {xin[2], xin[8], m_down[0], m_down[1],
                    m_down[2], m_down[3], m_down[4], m_down[5]};
    v2f t4c[4], h_act[1];
    lin2<8,4,true>(ha_in, t4c, P.w[HA1], P.b[HA1]);
    lin2<4,1,false>(t4c, h_act, P.w[HA2], P.b[HA2]);   // acc pair = {rowA, rowB}

    // ---- k_act: [k, kd, h_down(4)] -> 4 -> 1 ----
    v2f ka_in[6] = {xin[3], xin[9], h_down[0], h_down[1], h_down[2], h_down[3]};
    v2f t4d[4], k_act[1];
    lin2<6,4,true>(ka_in, t4d, P.w[KA1], P.b[KA1]);
    lin2<4,1,false>(t4d, k_act, P.w[KA2], P.b[KA2]);

    // ---- f_act: [f, fd, k_down(2)] -> 4 -> 1 ----
    v2f fa_in[4] = {xin[4], xin[10], k_down[0], k_down[1]};
    v2f t4e[4], f_act[1];
    lin2<4,4,true>(fa_in, t4e, P.w[FA1], P.b[FA1]);
    lin2<4,1,false>(t4e, f_act, P.w[FA2], P.b[FA2]);

    // ---- store: [h_act, f_act, k_act] per row (guarded for tail) ----
    if (rowA < B) {
        float* po = out + (long long)rowA * 3;
        po[0] = h_act[0].x;
        po[1] = f_act[0].x;
        po[2] = k_act[0].x;
    }
    if (rowB < B) {
        float* po = out + (long long)rowB * 3;
        po[0] = h_act[0].y;
        po[1] = f_act[0].y;
        po[2] = k_act[0].y;
    }
}

extern "C" void kernel_launch(void* const* d_in, const int* in_sizes, int n_in,
                              void* d_out, int out_size, void* d_ws, size_t ws_size,
                              hipStream_t stream) {
    static const int wn[19] = {4,4,16,16,36,36,176,256,96,24,16,8,4,32,4,24,4,16,4};
    static const int bn[19] = {2,2,4,4,6,6,16,16,6,4,4,2,2,4,1,4,1,4,1};

    const float* x = (const float*)d_in[0];
    float* out = (float*)d_out;
    const int B = in_sizes[0] / 11;

    WPtrs P;
    for (int i = 0; i < 19; ++i) {
        P.w[i] = (const float*)d_in[1 + 2*i];
        P.b[i] = (const float*)d_in[2 + 2*i];
    }

    float* ws = (float*)d_ws;
    WDup D;
    int off = 0;
    for (int l = 0; l < 19; ++l) {
        D.w[l] = (const v2f*)(ws + off); off += 2 * wn[l];
        D.b[l] = (const v2f*)(ws + off); off += 2 * bn[l];
    }

    prep_kernel<<<19, BLOCK, 0, stream>>>(P, ws);   // one block per layer, ~2 us

    const long long rows_per_block = (long long)BLOCK * 2;
    const int blocks = (int)((B + rows_per_block - 1) / rows_per_block);
    pnet_kernel<<<blocks, BLOCK, 0, stream>>>(x, out, B, D);
}